// Round 1
// baseline (1348.223 us; speedup 1.0000x reference)
//
#include <hip/hip_runtime.h>
#include <math.h>

#define N_NODES 10000
#define E_EDGES 160000
#define E_TOT   170000   // E + self loops
#define MAXDEG  256
#define HMAX    6

// ---------------- graph CSR build (by dst) ----------------
__global__ void count_kernel(const int* __restrict__ ei, int* __restrict__ deg) {
    int e = blockIdx.x * 256 + threadIdx.x;
    if (e >= E_TOT) return;
    int dst = (e < E_EDGES) ? ei[E_EDGES + e] : (e - E_EDGES);
    atomicAdd(&deg[dst], 1);
}

__global__ void scan_kernel(const int* __restrict__ deg, int* __restrict__ rowptr) {
    __shared__ int sums[1024];
    int t = threadIdx.x;
    const int CH = (N_NODES + 1023) / 1024;
    int base = t * CH;
    int s = 0;
    for (int j = 0; j < CH; j++) { int i = base + j; if (i < N_NODES) s += deg[i]; }
    sums[t] = s; __syncthreads();
    for (int off = 1; off < 1024; off <<= 1) {
        int v = (t >= off) ? sums[t - off] : 0;
        __syncthreads();
        sums[t] += v;
        __syncthreads();
    }
    int excl = (t == 0) ? 0 : sums[t - 1];
    for (int j = 0; j < CH; j++) {
        int i = base + j;
        if (i < N_NODES) { rowptr[i] = excl; excl += deg[i]; }
    }
    if (t == 1023) rowptr[N_NODES] = sums[1023];
}

__global__ void cursor_init(const int* __restrict__ rowptr, int* __restrict__ cursor) {
    int i = blockIdx.x * 256 + threadIdx.x;
    if (i < N_NODES) cursor[i] = rowptr[i];
}

__global__ void scatter_kernel(const int* __restrict__ ei, int* __restrict__ cursor,
                               int* __restrict__ perm_src) {
    int e = blockIdx.x * 256 + threadIdx.x;
    if (e >= E_TOT) return;
    int src, dst;
    if (e < E_EDGES) { src = ei[e]; dst = ei[E_EDGES + e]; }
    else { src = e - E_EDGES; dst = src; }
    int pos = atomicAdd(&cursor[dst], 1);
    perm_src[pos] = src;
}

// ---------------- f32 tiled GEMM: C[i,o] = sum_k A[i,k]*B[o,k] ----------------
__global__ __launch_bounds__(256) void gemm_nt(const float* __restrict__ A,
                                               const float* __restrict__ B,
                                               float* __restrict__ C,
                                               int M, int Nn, int K) {
    __shared__ float As[16][65];
    __shared__ float Bs[16][65];
    int bm = blockIdx.y * 64, bn = blockIdx.x * 64;
    int tid = threadIdx.x;
    int lk = tid & 15, lm0 = tid >> 4;
    int tc = tid & 15, tr = tid >> 4;
    float acc[4][4];
#pragma unroll
    for (int i = 0; i < 4; i++)
#pragma unroll
        for (int j = 0; j < 4; j++) acc[i][j] = 0.f;

    for (int k0 = 0; k0 < K; k0 += 16) {
#pragma unroll
        for (int p = 0; p < 4; p++) {
            int m = lm0 + p * 16;
            int gm = bm + m, gk = k0 + lk;
            As[lk][m] = (gm < M && gk < K) ? A[(size_t)gm * K + gk] : 0.f;
            int gn = bn + m;
            Bs[lk][m] = (gn < Nn && gk < K) ? B[(size_t)gn * K + gk] : 0.f;
        }
        __syncthreads();
#pragma unroll
        for (int kk = 0; kk < 16; kk++) {
            float a4[4], b4[4];
#pragma unroll
            for (int j = 0; j < 4; j++) { a4[j] = As[kk][tr * 4 + j]; b4[j] = Bs[kk][tc * 4 + j]; }
#pragma unroll
            for (int i = 0; i < 4; i++)
#pragma unroll
                for (int j = 0; j < 4; j++) acc[i][j] += a4[i] * b4[j];
        }
        __syncthreads();
    }
#pragma unroll
    for (int i = 0; i < 4; i++) {
        int row = bm + tr * 4 + i;
        if (row >= M) continue;
#pragma unroll
        for (int j = 0; j < 4; j++) {
            int col = bn + tc * 4 + j;
            if (col < Nn) C[(size_t)row * Nn + col] = acc[i][j];
        }
    }
}

// ---------------- per-node attention coefficients ----------------
__global__ __launch_bounds__(256) void attn_kernel(const float* __restrict__ h,
        const float* __restrict__ a_s, const float* __restrict__ a_d,
        float* __restrict__ esrc, float* __restrict__ edst, int HC, int C, int H) {
    int node = blockIdx.x;
    int tid = threadIdx.x;
    __shared__ float ss[HMAX], sd[HMAX];
    if (tid < H) { ss[tid] = 0.f; sd[tid] = 0.f; }
    __syncthreads();
    float ps[HMAX], pd[HMAX];
#pragma unroll
    for (int hh = 0; hh < HMAX; hh++) { ps[hh] = 0.f; pd[hh] = 0.f; }
    const float* hrow = h + (size_t)node * HC;
    for (int c = tid; c < HC; c += 256) {
        float v = hrow[c];
        int hh = c / C;
        ps[hh] += v * a_s[c];
        pd[hh] += v * a_d[c];
    }
    for (int hh = 0; hh < H; hh++) {
        float v1 = ps[hh], v2 = pd[hh];
        for (int off = 32; off; off >>= 1) { v1 += __shfl_xor(v1, off); v2 += __shfl_xor(v2, off); }
        if ((tid & 63) == 0) { atomicAdd(&ss[hh], v1); atomicAdd(&sd[hh], v2); }
    }
    __syncthreads();
    if (tid < H) {
        esrc[(size_t)node * H + tid] = ss[tid];
        edst[(size_t)node * H + tid] = sd[tid];
    }
}

// ---------------- per-dst softmax + weighted gather (no atomics) ----------------
__global__ __launch_bounds__(256) void aggregate_kernel(const float* __restrict__ h,
        const float* __restrict__ esrc, const float* __restrict__ edst,
        const int* __restrict__ rowptr, const int* __restrict__ perm_src,
        float* __restrict__ obuf, int HC, int C, int H) {
    int d = blockIdx.x;
    int tid = threadIdx.x;
    __shared__ int srcs[MAXDEG];
    __shared__ float al[HMAX * MAXDEG];
    int r0 = rowptr[d];
    int deg = rowptr[d + 1] - r0;
    if (deg > MAXDEG) deg = MAXDEG;
    for (int t = tid; t < deg; t += 256) srcs[t] = perm_src[r0 + t];
    __syncthreads();
    for (int idx = tid; idx < deg * H; idx += 256) {
        int hh = idx / deg, t = idx - hh * deg;
        float e = esrc[(size_t)srcs[t] * H + hh] + edst[(size_t)d * H + hh];
        e = (e > 0.f) ? e : 0.2f * e;
        al[hh * MAXDEG + t] = e;
    }
    __syncthreads();
    if (tid < H) {
        float m = -1e30f;
        for (int t = 0; t < deg; t++) m = fmaxf(m, al[tid * MAXDEG + t]);
        float s = 0.f;
        for (int t = 0; t < deg; t++) {
            float w = __expf(al[tid * MAXDEG + t] - m);
            al[tid * MAXDEG + t] = w;
            s += w;
        }
        float inv = 1.f / fmaxf(s, 1e-16f);
        for (int t = 0; t < deg; t++) al[tid * MAXDEG + t] *= inv;
    }
    __syncthreads();
    if (C == 256) {  // HC == 1024, float4 per thread
        int c0 = tid * 4;
        int hh = c0 >> 8;
        float4 acc = make_float4(0.f, 0.f, 0.f, 0.f);
#pragma unroll 2
        for (int t = 0; t < deg; t++) {
            float a = al[hh * MAXDEG + t];
            const float4 hv = *(const float4*)(h + (size_t)srcs[t] * HC + c0);
            acc.x += a * hv.x; acc.y += a * hv.y; acc.z += a * hv.z; acc.w += a * hv.w;
        }
        *(float4*)(obuf + (size_t)d * HC + c0) = acc;
    } else {
        for (int c = tid; c < HC; c += 256) {
            int hh = c / C;
            float acc = 0.f;
#pragma unroll 2
            for (int t = 0; t < deg; t++)
                acc += al[hh * MAXDEG + t] * h[(size_t)srcs[t] * HC + c];
            obuf[(size_t)d * HC + c] = acc;
        }
    }
}

// ---------------- epilogues ----------------
__global__ void ep_elu(const float* __restrict__ o, const float* __restrict__ b,
                       float* __restrict__ x, int total) {
    int i = blockIdx.x * 256 + threadIdx.x;
    if (i >= total) return;
    int c = i & 1023;
    float v = o[i] + b[c];
    x[i] = (v > 0.f) ? v : expm1f(v);
}

__global__ void ep_elu_res(const float* __restrict__ o, const float* __restrict__ b,
                           float* __restrict__ x, int total) {
    int i = blockIdx.x * 256 + threadIdx.x;
    if (i >= total) return;
    int c = i & 1023;
    float v = o[i] + b[c] + x[i];
    x[i] = (v > 0.f) ? v : expm1f(v);
}

__global__ void ep_final(const float* __restrict__ o, const float* __restrict__ b3,
                         float* __restrict__ out) {
    int i = blockIdx.x * 256 + threadIdx.x;
    if (i >= N_NODES * 121) return;
    int node = i / 121, c = i - node * 121;
    float s = 0.f;
#pragma unroll
    for (int hh = 0; hh < 6; hh++) s += o[(size_t)node * 726 + hh * 121 + c];
    s = s * (1.f / 6.f) + b3[c];
    out[i] = 1.f / (1.f + __expf(-s));
}

// ---------------- launcher ----------------
extern "C" void kernel_launch(void* const* d_in, const int* in_sizes, int n_in,
                              void* d_out, int out_size, void* d_ws, size_t ws_size,
                              hipStream_t stream) {
    const float* x   = (const float*)d_in[0];
    const int*   ei  = (const int*)d_in[1];
    const float* W1  = (const float*)d_in[2];
    const float* as1 = (const float*)d_in[3];
    const float* ad1 = (const float*)d_in[4];
    const float* b1  = (const float*)d_in[5];
    const float* W2  = (const float*)d_in[6];
    const float* as2 = (const float*)d_in[7];
    const float* ad2 = (const float*)d_in[8];
    const float* b2  = (const float*)d_in[9];
    const float* W3  = (const float*)d_in[10];
    const float* as3 = (const float*)d_in[11];
    const float* ad3 = (const float*)d_in[12];
    const float* b3  = (const float*)d_in[13];
    float* out = (float*)d_out;

    float* fws  = (float*)d_ws;
    float* hbuf = fws;                 // N*1024
    float* xbuf = fws + 10240000;      // N*1024
    float* obuf = fws + 20480000;      // N*1024
    float* esrc = fws + 30720000;      // N*HMAX
    float* edst = fws + 30780000;      // N*HMAX
    int*   iws  = (int*)(fws + 30840000);
    int* deg    = iws;                 // N
    int* rowptr = iws + N_NODES;       // N+1
    int* cursor = iws + 2 * N_NODES + 1;   // N
    int* perm   = iws + 3 * N_NODES + 1;   // E_TOT

    hipMemsetAsync(deg, 0, N_NODES * sizeof(int), stream);
    count_kernel<<<(E_TOT + 255) / 256, 256, 0, stream>>>(ei, deg);
    scan_kernel<<<1, 1024, 0, stream>>>(deg, rowptr);
    cursor_init<<<(N_NODES + 255) / 256, 256, 0, stream>>>(rowptr, cursor);
    scatter_kernel<<<(E_TOT + 255) / 256, 256, 0, stream>>>(ei, cursor, perm);

    dim3 blk(256);
    // ---- layer 1: K=50, H=4, C=256 ----
    {
        dim3 g((1024 + 63) / 64, (N_NODES + 63) / 64);
        gemm_nt<<<g, blk, 0, stream>>>(x, W1, hbuf, N_NODES, 1024, 50);
        attn_kernel<<<N_NODES, blk, 0, stream>>>(hbuf, as1, ad1, esrc, edst, 1024, 256, 4);
        aggregate_kernel<<<N_NODES, blk, 0, stream>>>(hbuf, esrc, edst, rowptr, perm, obuf, 1024, 256, 4);
        ep_elu<<<(N_NODES * 1024 + 255) / 256, blk, 0, stream>>>(obuf, b1, xbuf, N_NODES * 1024);
    }
    // ---- layer 2: K=1024, H=4, C=256, residual ----
    {
        dim3 g((1024 + 63) / 64, (N_NODES + 63) / 64);
        gemm_nt<<<g, blk, 0, stream>>>(xbuf, W2, hbuf, N_NODES, 1024, 1024);
        attn_kernel<<<N_NODES, blk, 0, stream>>>(hbuf, as2, ad2, esrc, edst, 1024, 256, 4);
        aggregate_kernel<<<N_NODES, blk, 0, stream>>>(hbuf, esrc, edst, rowptr, perm, obuf, 1024, 256, 4);
        ep_elu_res<<<(N_NODES * 1024 + 255) / 256, blk, 0, stream>>>(obuf, b2, xbuf, N_NODES * 1024);
    }
    // ---- layer 3: K=1024, H=6, C=121, mean heads + sigmoid ----
    {
        dim3 g((726 + 63) / 64, (N_NODES + 63) / 64);
        gemm_nt<<<g, blk, 0, stream>>>(xbuf, W3, hbuf, N_NODES, 726, 1024);
        attn_kernel<<<N_NODES, blk, 0, stream>>>(hbuf, as3, ad3, esrc, edst, 726, 121, 6);
        aggregate_kernel<<<N_NODES, blk, 0, stream>>>(hbuf, esrc, edst, rowptr, perm, obuf, 726, 121, 6);
        ep_final<<<(N_NODES * 121 + 255) / 256, blk, 0, stream>>>(obuf, b3, out);
    }
}

// Round 2
// 580.704 us; speedup vs baseline: 2.3217x; 2.3217x over previous
//
#include <hip/hip_runtime.h>
#include <math.h>

#define N_NODES 10000
#define E_EDGES 160000
#define E_TOT   170000   // E + self loops
#define MAXDEG  256
#define HMAX    6
#define MPAD    10112    // 79 * 128

typedef _Float16 f16x8 __attribute__((ext_vector_type(8)));
typedef float    f32x4 __attribute__((ext_vector_type(4)));

// ---------------- graph CSR build (by dst) ----------------
__global__ void count_kernel(const int* __restrict__ ei, int* __restrict__ deg) {
    int e = blockIdx.x * 256 + threadIdx.x;
    if (e >= E_TOT) return;
    int dst = (e < E_EDGES) ? ei[E_EDGES + e] : (e - E_EDGES);
    atomicAdd(&deg[dst], 1);
}

__global__ void scan_kernel(const int* __restrict__ deg, int* __restrict__ rowptr) {
    __shared__ int sums[1024];
    int t = threadIdx.x;
    const int CH = (N_NODES + 1023) / 1024;
    int base = t * CH;
    int s = 0;
    for (int j = 0; j < CH; j++) { int i = base + j; if (i < N_NODES) s += deg[i]; }
    sums[t] = s; __syncthreads();
    for (int off = 1; off < 1024; off <<= 1) {
        int v = (t >= off) ? sums[t - off] : 0;
        __syncthreads();
        sums[t] += v;
        __syncthreads();
    }
    int excl = (t == 0) ? 0 : sums[t - 1];
    for (int j = 0; j < CH; j++) {
        int i = base + j;
        if (i < N_NODES) { rowptr[i] = excl; excl += deg[i]; }
    }
    if (t == 1023) rowptr[N_NODES] = sums[1023];
}

__global__ void cursor_init(const int* __restrict__ rowptr, int* __restrict__ cursor) {
    int i = blockIdx.x * 256 + threadIdx.x;
    if (i < N_NODES) cursor[i] = rowptr[i];
}

__global__ void scatter_kernel(const int* __restrict__ ei, int* __restrict__ cursor,
                               int* __restrict__ perm_src) {
    int e = blockIdx.x * 256 + threadIdx.x;
    if (e >= E_TOT) return;
    int src, dst;
    if (e < E_EDGES) { src = ei[e]; dst = ei[E_EDGES + e]; }
    else { src = e - E_EDGES; dst = src; }
    int pos = atomicAdd(&cursor[dst], 1);
    perm_src[pos] = src;
}

// ---------------- f32 -> f16 zero-padded conversion ----------------
__global__ void cvt_pad(const float* __restrict__ in, _Float16* __restrict__ out,
                        int rows, int cols, int colsPad, int totalPad) {
    int i = blockIdx.x * 256 + threadIdx.x;
    if (i >= totalPad) return;
    int r = i / colsPad, c = i - r * colsPad;
    float v = (r < rows && c < cols) ? in[(size_t)r * cols + c] : 0.f;
    out[i] = (_Float16)v;
}

__global__ void zero_tail(_Float16* __restrict__ p, int start, int count) {
    int i = blockIdx.x * 256 + threadIdx.x;
    if (i < count) p[start + i] = (_Float16)0.f;
}

// ---------------- fp16 MFMA GEMM: C[m,n] = sum_k A[m,k]*B[n,k] ----------------
// A: [MPAD, Kp] fp16 (zero-padded), B: [Npad, Kp] fp16, C: [M, ldc] f32.
// 128x128 tile, BK=64, 4 waves, global_load_lds w/ pre-swizzled source.
__device__ __forceinline__ void gload_lds(const _Float16* g, _Float16* l) {
    __builtin_amdgcn_global_load_lds(
        (const __attribute__((address_space(1))) void*)g,
        (__attribute__((address_space(3))) void*)l, 16, 0, 0);
}

__global__ __launch_bounds__(256) void gemm_mfma(const _Float16* __restrict__ A,
                                                 const _Float16* __restrict__ B,
                                                 float* __restrict__ C,
                                                 int M, int Nn, int Kp, int ldc) {
    __shared__ _Float16 lds[16384];          // A tile [128][64] + B tile [128][64] = 32 KB
    const int tid  = threadIdx.x;
    const int bm   = blockIdx.y * 128, bn = blockIdx.x * 128;
    const int w    = tid >> 6, lane = tid & 63;
    const int wr   = w >> 1,   wc   = w & 1; // wave owns 64x64 at (wr*64, wc*64)
    const int la   = lane & 15, g = lane >> 4;

    f32x4 acc[4][4] = {};

    // staging geometry: instruction i covers rows i*32 + (tid>>3); 8 lanes per row
    const int srow = tid >> 3;               // 0..31
    const int skb0 = (tid & 7) * 16;         // byte col before swizzle

    for (int k0 = 0; k0 < Kp; k0 += 64) {
        __syncthreads();                     // previous tile's readers done
#pragma unroll
        for (int i = 0; i < 4; i++) {        // A tile
            int row = i * 32 + srow;
            int kb  = skb0 ^ ((row & 7) << 4);           // pre-swizzled source
            gload_lds(A + (size_t)(bm + row) * Kp + k0 + (kb >> 1),
                      lds + i * 2048 + w * 512);          // linear dest: base+lane*16
        }
#pragma unroll
        for (int i = 0; i < 4; i++) {        // B tile
            int row = i * 32 + srow;
            int kb  = skb0 ^ ((row & 7) << 4);
            gload_lds(B + (size_t)(bn + row) * Kp + k0 + (kb >> 1),
                      lds + 8192 + i * 2048 + w * 512);
        }
        asm volatile("s_waitcnt vmcnt(0)");
        __syncthreads();
#pragma unroll
        for (int s = 0; s < 2; s++) {
            f16x8 af[4], bf[4];
#pragma unroll
            for (int m = 0; m < 4; m++) {
                int r  = wr * 64 + m * 16 + la;
                int bc = (s * 64 + g * 16) ^ ((r & 7) << 4);   // swizzled read
                af[m] = *(const f16x8*)(lds + r * 64 + (bc >> 1));
            }
#pragma unroll
            for (int n = 0; n < 4; n++) {
                int r  = wc * 64 + n * 16 + la;
                int bc = (s * 64 + g * 16) ^ ((r & 7) << 4);
                bf[n] = *(const f16x8*)(lds + 8192 + r * 64 + (bc >> 1));
            }
#pragma unroll
            for (int m = 0; m < 4; m++)
#pragma unroll
                for (int n = 0; n < 4; n++)
                    acc[m][n] = __builtin_amdgcn_mfma_f32_16x16x32_f16(af[m], bf[n], acc[m][n], 0, 0, 0);
        }
    }
    // epilogue: D row=(lane>>4)*4+reg, col=lane&15
#pragma unroll
    for (int m = 0; m < 4; m++) {
#pragma unroll
        for (int n = 0; n < 4; n++) {
            int col = bn + wc * 64 + n * 16 + la;
            if (col >= Nn) continue;
#pragma unroll
            for (int r = 0; r < 4; r++) {
                int row = bm + wr * 64 + m * 16 + g * 4 + r;
                if (row < M) C[(size_t)row * ldc + col] = acc[m][n][r];
            }
        }
    }
}

// ---------------- per-node attention coefficients ----------------
__global__ __launch_bounds__(256) void attn_kernel(const float* __restrict__ h,
        const float* __restrict__ a_s, const float* __restrict__ a_d,
        float* __restrict__ esrc, float* __restrict__ edst, int HC, int C, int H) {
    int node = blockIdx.x;
    int tid = threadIdx.x;
    __shared__ float ss[HMAX], sd[HMAX];
    if (tid < H) { ss[tid] = 0.f; sd[tid] = 0.f; }
    __syncthreads();
    float ps[HMAX], pd[HMAX];
#pragma unroll
    for (int hh = 0; hh < HMAX; hh++) { ps[hh] = 0.f; pd[hh] = 0.f; }
    const float* hrow = h + (size_t)node * HC;
    for (int c = tid; c < HC; c += 256) {
        float v = hrow[c];
        int hh = c / C;
        ps[hh] += v * a_s[c];
        pd[hh] += v * a_d[c];
    }
    for (int hh = 0; hh < H; hh++) {
        float v1 = ps[hh], v2 = pd[hh];
        for (int off = 32; off; off >>= 1) { v1 += __shfl_xor(v1, off); v2 += __shfl_xor(v2, off); }
        if ((tid & 63) == 0) { atomicAdd(&ss[hh], v1); atomicAdd(&sd[hh], v2); }
    }
    __syncthreads();
    if (tid < H) {
        esrc[(size_t)node * H + tid] = ss[tid];
        edst[(size_t)node * H + tid] = sd[tid];
    }
}

// ---------------- per-dst softmax + weighted gather (no atomics) ----------------
__global__ __launch_bounds__(256) void aggregate_kernel(const float* __restrict__ h,
        const float* __restrict__ esrc, const float* __restrict__ edst,
        const int* __restrict__ rowptr, const int* __restrict__ perm_src,
        float* __restrict__ obuf, int HC, int C, int H) {
    int d = blockIdx.x;
    int tid = threadIdx.x;
    __shared__ int srcs[MAXDEG];
    __shared__ float al[HMAX * MAXDEG];
    int r0 = rowptr[d];
    int deg = rowptr[d + 1] - r0;
    if (deg > MAXDEG) deg = MAXDEG;
    for (int t = tid; t < deg; t += 256) srcs[t] = perm_src[r0 + t];
    __syncthreads();
    for (int idx = tid; idx < deg * H; idx += 256) {
        int hh = idx / deg, t = idx - hh * deg;
        float e = esrc[(size_t)srcs[t] * H + hh] + edst[(size_t)d * H + hh];
        e = (e > 0.f) ? e : 0.2f * e;
        al[hh * MAXDEG + t] = e;
    }
    __syncthreads();
    if (tid < H) {
        float m = -1e30f;
        for (int t = 0; t < deg; t++) m = fmaxf(m, al[tid * MAXDEG + t]);
        float s = 0.f;
        for (int t = 0; t < deg; t++) {
            float w = __expf(al[tid * MAXDEG + t] - m);
            al[tid * MAXDEG + t] = w;
            s += w;
        }
        float inv = 1.f / fmaxf(s, 1e-16f);
        for (int t = 0; t < deg; t++) al[tid * MAXDEG + t] *= inv;
    }
    __syncthreads();
    if (C == 256) {  // HC == 1024, float4 per thread
        int c0 = tid * 4;
        int hh = c0 >> 8;
        float4 acc = make_float4(0.f, 0.f, 0.f, 0.f);
#pragma unroll 2
        for (int t = 0; t < deg; t++) {
            float a = al[hh * MAXDEG + t];
            const float4 hv = *(const float4*)(h + (size_t)srcs[t] * HC + c0);
            acc.x += a * hv.x; acc.y += a * hv.y; acc.z += a * hv.z; acc.w += a * hv.w;
        }
        *(float4*)(obuf + (size_t)d * HC + c0) = acc;
    } else {
        for (int c = tid; c < HC; c += 256) {
            int hh = c / C;
            float acc = 0.f;
#pragma unroll 2
            for (int t = 0; t < deg; t++)
                acc += al[hh * MAXDEG + t] * h[(size_t)srcs[t] * HC + c];
            obuf[(size_t)d * HC + c] = acc;
        }
    }
}

// ---------------- epilogues (fused fp16 mirror for next GEMM) ----------------
__global__ void ep_elu(const float* __restrict__ o, const float* __restrict__ b,
                       float* __restrict__ x, _Float16* __restrict__ xh, int total) {
    int i = blockIdx.x * 256 + threadIdx.x;
    if (i >= total) return;
    int c = i & 1023;
    float v = o[i] + b[c];
    v = (v > 0.f) ? v : expm1f(v);
    x[i] = v;
    xh[i] = (_Float16)v;
}

__global__ void ep_elu_res(const float* __restrict__ o, const float* __restrict__ b,
                           float* __restrict__ x, _Float16* __restrict__ xh, int total) {
    int i = blockIdx.x * 256 + threadIdx.x;
    if (i >= total) return;
    int c = i & 1023;
    float v = o[i] + b[c] + x[i];
    v = (v > 0.f) ? v : expm1f(v);
    x[i] = v;
    xh[i] = (_Float16)v;
}

__global__ void ep_final(const float* __restrict__ o, const float* __restrict__ b3,
                         float* __restrict__ out) {
    int i = blockIdx.x * 256 + threadIdx.x;
    if (i >= N_NODES * 121) return;
    int node = i / 121, c = i - node * 121;
    float s = 0.f;
#pragma unroll
    for (int hh = 0; hh < 6; hh++) s += o[(size_t)node * 726 + hh * 121 + c];
    s = s * (1.f / 6.f) + b3[c];
    out[i] = 1.f / (1.f + __expf(-s));
}

// ---------------- launcher ----------------
extern "C" void kernel_launch(void* const* d_in, const int* in_sizes, int n_in,
                              void* d_out, int out_size, void* d_ws, size_t ws_size,
                              hipStream_t stream) {
    const float* x   = (const float*)d_in[0];
    const int*   ei  = (const int*)d_in[1];
    const float* W1  = (const float*)d_in[2];
    const float* as1 = (const float*)d_in[3];
    const float* ad1 = (const float*)d_in[4];
    const float* b1  = (const float*)d_in[5];
    const float* W2  = (const float*)d_in[6];
    const float* as2 = (const float*)d_in[7];
    const float* ad2 = (const float*)d_in[8];
    const float* b2  = (const float*)d_in[9];
    const float* W3  = (const float*)d_in[10];
    const float* as3 = (const float*)d_in[11];
    const float* ad3 = (const float*)d_in[12];
    const float* b3  = (const float*)d_in[13];
    float* out = (float*)d_out;

    float* fws  = (float*)d_ws;
    float* hbuf = fws;                 // N*1024
    float* xbuf = fws + 10240000;      // N*1024
    float* obuf = fws + 20480000;      // N*1024
    float* esrc = fws + 30720000;      // N*HMAX
    float* edst = fws + 30780000;      // N*HMAX
    int*   iws  = (int*)(fws + 30840000);
    int* deg    = iws;                 // N
    int* rowptr = iws + N_NODES;       // N+1
    int* cursor = iws + 2 * N_NODES + 1;   // N
    int* perm   = iws + 3 * N_NODES + 1;   // E_TOT
    _Float16* h16 = (_Float16*)(fws + 31040016);
    _Float16* xh  = h16;                       // MPAD*1024
    _Float16* xh1 = xh + (size_t)MPAD * 1024;  // MPAD*64
    _Float16* W1h = xh1 + (size_t)MPAD * 64;   // 1024*64
    _Float16* W2h = W1h + 1024 * 64;           // 1024*1024
    _Float16* W3h = W2h + 1024 * 1024;         // 768*1024

    hipMemsetAsync(deg, 0, N_NODES * sizeof(int), stream);
    count_kernel<<<(E_TOT + 255) / 256, 256, 0, stream>>>(ei, deg);
    scan_kernel<<<1, 1024, 0, stream>>>(deg, rowptr);
    cursor_init<<<(N_NODES + 255) / 256, 256, 0, stream>>>(rowptr, cursor);
    scatter_kernel<<<(E_TOT + 255) / 256, 256, 0, stream>>>(ei, cursor, perm);

    dim3 blk(256);
    // fp16 conversions (deterministic every call)
    cvt_pad<<<(MPAD * 64 + 255) / 256, blk, 0, stream>>>(x, xh1, N_NODES, 50, 64, MPAD * 64);
    cvt_pad<<<(1024 * 64 + 255) / 256, blk, 0, stream>>>(W1, W1h, 1024, 50, 64, 1024 * 64);
    cvt_pad<<<(1024 * 1024 + 255) / 256, blk, 0, stream>>>(W2, W2h, 1024, 1024, 1024, 1024 * 1024);
    cvt_pad<<<(768 * 1024 + 255) / 256, blk, 0, stream>>>(W3, W3h, 726, 1024, 1024, 768 * 1024);
    zero_tail<<<((MPAD - N_NODES) * 1024 + 255) / 256, blk, 0, stream>>>(xh, N_NODES * 1024, (MPAD - N_NODES) * 1024);

    // ---- layer 1: K=50->64, H=4, C=256 ----
    {
        dim3 g(8, 79);
        gemm_mfma<<<g, blk, 0, stream>>>(xh1, W1h, hbuf, N_NODES, 1024, 64, 1024);
        attn_kernel<<<N_NODES, blk, 0, stream>>>(hbuf, as1, ad1, esrc, edst, 1024, 256, 4);
        aggregate_kernel<<<N_NODES, blk, 0, stream>>>(hbuf, esrc, edst, rowptr, perm, obuf, 1024, 256, 4);
        ep_elu<<<(N_NODES * 1024 + 255) / 256, blk, 0, stream>>>(obuf, b1, xbuf, xh, N_NODES * 1024);
    }
    // ---- layer 2: K=1024, H=4, C=256, residual ----
    {
        dim3 g(8, 79);
        gemm_mfma<<<g, blk, 0, stream>>>(xh, W2h, hbuf, N_NODES, 1024, 1024, 1024);
        attn_kernel<<<N_NODES, blk, 0, stream>>>(hbuf, as2, ad2, esrc, edst, 1024, 256, 4);
        aggregate_kernel<<<N_NODES, blk, 0, stream>>>(hbuf, esrc, edst, rowptr, perm, obuf, 1024, 256, 4);
        ep_elu_res<<<(N_NODES * 1024 + 255) / 256, blk, 0, stream>>>(obuf, b2, xbuf, xh, N_NODES * 1024);
    }
    // ---- layer 3: K=1024, H=6, C=121, mean heads + sigmoid ----
    {
        dim3 g(6, 79);
        gemm_mfma<<<g, blk, 0, stream>>>(xh, W3h, hbuf, N_NODES, 726, 1024, 726);
        attn_kernel<<<N_NODES, blk, 0, stream>>>(hbuf, as3, ad3, esrc, edst, 726, 121, 6);
        aggregate_kernel<<<N_NODES, blk, 0, stream>>>(hbuf, esrc, edst, rowptr, perm, obuf, 726, 121, 6);
        ep_final<<<(N_NODES * 121 + 255) / 256, blk, 0, stream>>>(obuf, b3, out);
    }
}

// Round 3
// 392.427 us; speedup vs baseline: 3.4356x; 1.4798x over previous
//
#include <hip/hip_runtime.h>
#include <math.h>

#define N_NODES 10000
#define E_EDGES 160000
#define E_TOT   170000   // E + self loops
#define MAXDEG  256
#define HMAX    6
#define MPAD    10112    // 79 * 128

typedef _Float16 f16x8 __attribute__((ext_vector_type(8)));
typedef _Float16 f16x4 __attribute__((ext_vector_type(4)));
typedef float    f32x4 __attribute__((ext_vector_type(4)));

// ---------------- graph CSR build (by dst) ----------------
__global__ void count_kernel(const int* __restrict__ ei, int* __restrict__ deg) {
    int e = blockIdx.x * 256 + threadIdx.x;
    if (e >= E_TOT) return;
    int dst = (e < E_EDGES) ? ei[E_EDGES + e] : (e - E_EDGES);
    atomicAdd(&deg[dst], 1);
}

__global__ void scan_kernel(const int* __restrict__ deg, int* __restrict__ rowptr) {
    __shared__ int sums[1024];
    int t = threadIdx.x;
    const int CH = (N_NODES + 1023) / 1024;
    int base = t * CH;
    int s = 0;
    for (int j = 0; j < CH; j++) { int i = base + j; if (i < N_NODES) s += deg[i]; }
    sums[t] = s; __syncthreads();
    for (int off = 1; off < 1024; off <<= 1) {
        int v = (t >= off) ? sums[t - off] : 0;
        __syncthreads();
        sums[t] += v;
        __syncthreads();
    }
    int excl = (t == 0) ? 0 : sums[t - 1];
    for (int j = 0; j < CH; j++) {
        int i = base + j;
        if (i < N_NODES) { rowptr[i] = excl; excl += deg[i]; }
    }
    if (t == 1023) rowptr[N_NODES] = sums[1023];
}

__global__ void cursor_init(const int* __restrict__ rowptr, int* __restrict__ cursor) {
    int i = blockIdx.x * 256 + threadIdx.x;
    if (i < N_NODES) cursor[i] = rowptr[i];
}

__global__ void scatter_kernel(const int* __restrict__ ei, int* __restrict__ cursor,
                               int* __restrict__ perm_src) {
    int e = blockIdx.x * 256 + threadIdx.x;
    if (e >= E_TOT) return;
    int src, dst;
    if (e < E_EDGES) { src = ei[e]; dst = ei[E_EDGES + e]; }
    else { src = e - E_EDGES; dst = src; }
    int pos = atomicAdd(&cursor[dst], 1);
    perm_src[pos] = src;
}

// ---------------- f32 -> f16 zero-padded conversion ----------------
__global__ void cvt_pad(const float* __restrict__ in, _Float16* __restrict__ out,
                        int rows, int cols, int colsPad, int totalPad) {
    int i = blockIdx.x * 256 + threadIdx.x;
    if (i >= totalPad) return;
    int r = i / colsPad, c = i - r * colsPad;
    float v = (r < rows && c < cols) ? in[(size_t)r * cols + c] : 0.f;
    out[i] = (_Float16)v;
}

__global__ void zero_tail(_Float16* __restrict__ p, int start, int count) {
    int i = blockIdx.x * 256 + threadIdx.x;
    if (i < count) p[start + i] = (_Float16)0.f;
}

// ---------------- fp16 MFMA GEMM: C16[m,n] = sum_k A[m,k]*B[n,k] (fp16 out) ----------------
__device__ __forceinline__ void gload_lds(const _Float16* g, _Float16* l) {
    __builtin_amdgcn_global_load_lds(
        (const __attribute__((address_space(1))) void*)g,
        (__attribute__((address_space(3))) void*)l, 16, 0, 0);
}

__global__ __launch_bounds__(256) void gemm_mfma(const _Float16* __restrict__ A,
                                                 const _Float16* __restrict__ B,
                                                 _Float16* __restrict__ C,
                                                 int M, int Nn, int Kp, int ldc) {
    __shared__ _Float16 lds[16384];          // A tile [128][64] + B tile [128][64] = 32 KB
    const int tid  = threadIdx.x;
    const int bm   = blockIdx.y * 128, bn = blockIdx.x * 128;
    const int w    = tid >> 6, lane = tid & 63;
    const int wr   = w >> 1,   wc   = w & 1; // wave owns 64x64 at (wr*64, wc*64)
    const int la   = lane & 15, g = lane >> 4;

    f32x4 acc[4][4] = {};

    const int srow = tid >> 3;               // 0..31
    const int skb0 = (tid & 7) * 16;         // byte col before swizzle

    for (int k0 = 0; k0 < Kp; k0 += 64) {
        __syncthreads();
#pragma unroll
        for (int i = 0; i < 4; i++) {        // A tile
            int row = i * 32 + srow;
            int kb  = skb0 ^ ((row & 7) << 4);
            gload_lds(A + (size_t)(bm + row) * Kp + k0 + (kb >> 1),
                      lds + i * 2048 + w * 512);
        }
#pragma unroll
        for (int i = 0; i < 4; i++) {        // B tile
            int row = i * 32 + srow;
            int kb  = skb0 ^ ((row & 7) << 4);
            gload_lds(B + (size_t)(bn + row) * Kp + k0 + (kb >> 1),
                      lds + 8192 + i * 2048 + w * 512);
        }
        asm volatile("s_waitcnt vmcnt(0)");
        __syncthreads();
#pragma unroll
        for (int s = 0; s < 2; s++) {
            f16x8 af[4], bf[4];
#pragma unroll
            for (int m = 0; m < 4; m++) {
                int r  = wr * 64 + m * 16 + la;
                int bc = (s * 64 + g * 16) ^ ((r & 7) << 4);
                af[m] = *(const f16x8*)(lds + r * 64 + (bc >> 1));
            }
#pragma unroll
            for (int n = 0; n < 4; n++) {
                int r  = wc * 64 + n * 16 + la;
                int bc = (s * 64 + g * 16) ^ ((r & 7) << 4);
                bf[n] = *(const f16x8*)(lds + 8192 + r * 64 + (bc >> 1));
            }
#pragma unroll
            for (int m = 0; m < 4; m++)
#pragma unroll
                for (int n = 0; n < 4; n++)
                    acc[m][n] = __builtin_amdgcn_mfma_f32_16x16x32_f16(af[m], bf[n], acc[m][n], 0, 0, 0);
        }
    }
    // epilogue: D row=(lane>>4)*4+reg, col=lane&15 ; write fp16
#pragma unroll
    for (int m = 0; m < 4; m++) {
#pragma unroll
        for (int n = 0; n < 4; n++) {
            int col = bn + wc * 64 + n * 16 + la;
            if (col >= Nn) continue;
#pragma unroll
            for (int r = 0; r < 4; r++) {
                int row = bm + wr * 64 + m * 16 + g * 4 + r;
                if (row < M) C[(size_t)row * ldc + col] = (_Float16)acc[m][n][r];
            }
        }
    }
}

// ---------------- per-node attention coefficients (fp16 h) ----------------
__global__ __launch_bounds__(256) void attn_kernel(const _Float16* __restrict__ h,
        const float* __restrict__ a_s, const float* __restrict__ a_d,
        float* __restrict__ esrc, float* __restrict__ edst,
        int ld, int HC, int C, int H) {
    int node = blockIdx.x;
    int tid = threadIdx.x;
    const _Float16* hrow = h + (size_t)node * ld;
    if (HC == 1024) {            // H==4: one wave per head, no atomics
        int c0 = tid * 4;
        int hh = c0 >> 8;        // == wave id
        f16x4 hv = *(const f16x4*)(hrow + c0);
        float v1 = 0.f, v2 = 0.f;
#pragma unroll
        for (int j = 0; j < 4; j++) {
            float v = (float)hv[j];
            v1 += v * a_s[c0 + j];
            v2 += v * a_d[c0 + j];
        }
        for (int off = 32; off; off >>= 1) { v1 += __shfl_xor(v1, off); v2 += __shfl_xor(v2, off); }
        if ((tid & 63) == 0) {
            esrc[(size_t)node * H + hh] = v1;
            edst[(size_t)node * H + hh] = v2;
        }
        return;
    }
    __shared__ float ss[HMAX], sd[HMAX];
    if (tid < H) { ss[tid] = 0.f; sd[tid] = 0.f; }
    __syncthreads();
    float ps[HMAX], pd[HMAX];
#pragma unroll
    for (int hh = 0; hh < HMAX; hh++) { ps[hh] = 0.f; pd[hh] = 0.f; }
    for (int c = tid; c < HC; c += 256) {
        float v = (float)hrow[c];
        int hh = c / C;
        ps[hh] += v * a_s[c];
        pd[hh] += v * a_d[c];
    }
    for (int hh = 0; hh < H; hh++) {
        float v1 = ps[hh], v2 = pd[hh];
        for (int off = 32; off; off >>= 1) { v1 += __shfl_xor(v1, off); v2 += __shfl_xor(v2, off); }
        if ((tid & 63) == 0) { atomicAdd(&ss[hh], v1); atomicAdd(&sd[hh], v2); }
    }
    __syncthreads();
    if (tid < H) {
        esrc[(size_t)node * H + tid] = ss[tid];
        edst[(size_t)node * H + tid] = sd[tid];
    }
}

// ---------------- big-layer aggregate: softmax + gather + bias/ELU(+res) fused ----------------
template<int RES>
__global__ __launch_bounds__(256) void agg_big(const _Float16* __restrict__ h,
        const float* __restrict__ esrc, const float* __restrict__ edst,
        const int* __restrict__ rowptr, const int* __restrict__ perm_src,
        const float* __restrict__ bias, float* __restrict__ xbuf,
        _Float16* __restrict__ xh) {
    int d = blockIdx.x;
    int tid = threadIdx.x;
    __shared__ int srcs[MAXDEG];
    __shared__ float al[4 * MAXDEG];
    int r0 = rowptr[d];
    int deg = rowptr[d + 1] - r0;
    if (deg > MAXDEG) deg = MAXDEG;
    for (int t = tid; t < deg; t += 256) srcs[t] = perm_src[r0 + t];
    __syncthreads();
    for (int idx = tid; idx < deg * 4; idx += 256) {
        int hh = idx / deg, t = idx - hh * deg;
        float e = esrc[(size_t)srcs[t] * 4 + hh] + edst[(size_t)d * 4 + hh];
        e = (e > 0.f) ? e : 0.2f * e;
        al[hh * MAXDEG + t] = e;
    }
    __syncthreads();
    if (tid < 4) {
        float m = -1e30f;
        for (int t = 0; t < deg; t++) m = fmaxf(m, al[tid * MAXDEG + t]);
        float s = 0.f;
        for (int t = 0; t < deg; t++) {
            float w = __expf(al[tid * MAXDEG + t] - m);
            al[tid * MAXDEG + t] = w;
            s += w;
        }
        float inv = 1.f / fmaxf(s, 1e-16f);
        for (int t = 0; t < deg; t++) al[tid * MAXDEG + t] *= inv;
    }
    __syncthreads();
    int c0 = tid * 4;
    const float* alh = al + (c0 >> 8) * MAXDEG;
    float4 acc = make_float4(0.f, 0.f, 0.f, 0.f);
#pragma unroll 2
    for (int t = 0; t < deg; t++) {
        float a = alh[t];
        f16x4 hv = *(const f16x4*)(h + (size_t)srcs[t] * 1024 + c0);
        acc.x += a * (float)hv[0]; acc.y += a * (float)hv[1];
        acc.z += a * (float)hv[2]; acc.w += a * (float)hv[3];
    }
    // fused epilogue: bias + (residual) + ELU -> xbuf (f32) + xh (fp16)
    size_t o = (size_t)d * 1024 + c0;
    float4 r = RES ? *(const float4*)(xbuf + o) : make_float4(0.f, 0.f, 0.f, 0.f);
    float v0 = acc.x + bias[c0 + 0] + r.x;
    float v1 = acc.y + bias[c0 + 1] + r.y;
    float v2 = acc.z + bias[c0 + 2] + r.z;
    float v3 = acc.w + bias[c0 + 3] + r.w;
    v0 = (v0 > 0.f) ? v0 : expm1f(v0);
    v1 = (v1 > 0.f) ? v1 : expm1f(v1);
    v2 = (v2 > 0.f) ? v2 : expm1f(v2);
    v3 = (v3 > 0.f) ? v3 : expm1f(v3);
    *(float4*)(xbuf + o) = make_float4(v0, v1, v2, v3);
    f16x4 hv; hv[0] = (_Float16)v0; hv[1] = (_Float16)v1; hv[2] = (_Float16)v2; hv[3] = (_Float16)v3;
    *(f16x4*)(xh + o) = hv;
}

// ---------------- layer-3 aggregate: softmax + gather + head-mean + sigmoid ----------------
__global__ __launch_bounds__(256) void agg_final(const _Float16* __restrict__ h,  // ld 768
        const float* __restrict__ esrc, const float* __restrict__ edst,
        const int* __restrict__ rowptr, const int* __restrict__ perm_src,
        const float* __restrict__ b3, float* __restrict__ out) {
    int d = blockIdx.x;
    int tid = threadIdx.x;
    __shared__ int srcs[MAXDEG];
    __shared__ float al[6 * MAXDEG];
    __shared__ float sO[726];
    int r0 = rowptr[d];
    int deg = rowptr[d + 1] - r0;
    if (deg > MAXDEG) deg = MAXDEG;
    for (int t = tid; t < deg; t += 256) srcs[t] = perm_src[r0 + t];
    __syncthreads();
    for (int idx = tid; idx < deg * 6; idx += 256) {
        int hh = idx / deg, t = idx - hh * deg;
        float e = esrc[(size_t)srcs[t] * 6 + hh] + edst[(size_t)d * 6 + hh];
        e = (e > 0.f) ? e : 0.2f * e;
        al[hh * MAXDEG + t] = e;
    }
    __syncthreads();
    if (tid < 6) {
        float m = -1e30f;
        for (int t = 0; t < deg; t++) m = fmaxf(m, al[tid * MAXDEG + t]);
        float s = 0.f;
        for (int t = 0; t < deg; t++) {
            float w = __expf(al[tid * MAXDEG + t] - m);
            al[tid * MAXDEG + t] = w;
            s += w;
        }
        float inv = 1.f / fmaxf(s, 1e-16f);
        for (int t = 0; t < deg; t++) al[tid * MAXDEG + t] *= inv;
    }
    __syncthreads();
#pragma unroll
    for (int j = 0; j < 3; j++) {
        int c = tid + j * 256;
        if (c < 726) {
            const float* alh = al + (c / 121) * MAXDEG;
            float acc = 0.f;
#pragma unroll 2
            for (int t = 0; t < deg; t++)
                acc += alh[t] * (float)h[(size_t)srcs[t] * 768 + c];
            sO[c] = acc;
        }
    }
    __syncthreads();
    if (tid < 121) {
        float s = 0.f;
#pragma unroll
        for (int hh = 0; hh < 6; hh++) s += sO[hh * 121 + tid];
        s = s * (1.f / 6.f) + b3[tid];
        out[(size_t)d * 121 + tid] = 1.f / (1.f + __expf(-s));
    }
}

// ---------------- launcher ----------------
extern "C" void kernel_launch(void* const* d_in, const int* in_sizes, int n_in,
                              void* d_out, int out_size, void* d_ws, size_t ws_size,
                              hipStream_t stream) {
    const float* x   = (const float*)d_in[0];
    const int*   ei  = (const int*)d_in[1];
    const float* W1  = (const float*)d_in[2];
    const float* as1 = (const float*)d_in[3];
    const float* ad1 = (const float*)d_in[4];
    const float* b1  = (const float*)d_in[5];
    const float* W2  = (const float*)d_in[6];
    const float* as2 = (const float*)d_in[7];
    const float* ad2 = (const float*)d_in[8];
    const float* b2  = (const float*)d_in[9];
    const float* W3  = (const float*)d_in[10];
    const float* as3 = (const float*)d_in[11];
    const float* ad3 = (const float*)d_in[12];
    const float* b3  = (const float*)d_in[13];
    float* out = (float*)d_out;

    float* fws  = (float*)d_ws;
    float* xbuf = fws;                      // N*1024 f32
    float* esrc = fws + 10240000;           // N*HMAX
    float* edst = fws + 10300000;           // N*HMAX
    int*   iws  = (int*)(fws + 10360000);
    int* deg    = iws;                      // N
    int* rowptr = iws + N_NODES;            // N+1
    int* cursor = iws + 2 * N_NODES + 1;    // N
    int* perm   = iws + 3 * N_NODES + 1;    // E_TOT
    _Float16* f16b = (_Float16*)(fws + 10560004);
    _Float16* xh  = f16b;                          // MPAD*1024
    _Float16* xh1 = xh + (size_t)MPAD * 1024;      // MPAD*64
    _Float16* W1h = xh1 + (size_t)MPAD * 64;       // 1024*64
    _Float16* W2h = W1h + 1024 * 64;               // 1024*1024
    _Float16* W3h = W2h + 1024 * 1024;             // 768*1024
    _Float16* h16 = W3h + 768 * 1024;              // MPAD*1024

    hipMemsetAsync(deg, 0, N_NODES * sizeof(int), stream);
    count_kernel<<<(E_TOT + 255) / 256, 256, 0, stream>>>(ei, deg);
    scan_kernel<<<1, 1024, 0, stream>>>(deg, rowptr);
    cursor_init<<<(N_NODES + 255) / 256, 256, 0, stream>>>(rowptr, cursor);
    scatter_kernel<<<(E_TOT + 255) / 256, 256, 0, stream>>>(ei, cursor, perm);

    dim3 blk(256);
    cvt_pad<<<(MPAD * 64 + 255) / 256, blk, 0, stream>>>(x, xh1, N_NODES, 50, 64, MPAD * 64);
    cvt_pad<<<(1024 * 64 + 255) / 256, blk, 0, stream>>>(W1, W1h, 1024, 50, 64, 1024 * 64);
    cvt_pad<<<(1024 * 1024 + 255) / 256, blk, 0, stream>>>(W2, W2h, 1024, 1024, 1024, 1024 * 1024);
    cvt_pad<<<(768 * 1024 + 255) / 256, blk, 0, stream>>>(W3, W3h, 726, 1024, 1024, 768 * 1024);
    zero_tail<<<((MPAD - N_NODES) * 1024 + 255) / 256, blk, 0, stream>>>(xh, N_NODES * 1024, (MPAD - N_NODES) * 1024);

    // ---- layer 1: K=50->64, H=4, C=256 ----
    {
        dim3 g(8, 79);
        gemm_mfma<<<g, blk, 0, stream>>>(xh1, W1h, h16, N_NODES, 1024, 64, 1024);
        attn_kernel<<<N_NODES, blk, 0, stream>>>(h16, as1, ad1, esrc, edst, 1024, 1024, 256, 4);
        agg_big<0><<<N_NODES, blk, 0, stream>>>(h16, esrc, edst, rowptr, perm, b1, xbuf, xh);
    }
    // ---- layer 2: K=1024, H=4, C=256, residual ----
    {
        dim3 g(8, 79);
        gemm_mfma<<<g, blk, 0, stream>>>(xh, W2h, h16, N_NODES, 1024, 1024, 1024);
        attn_kernel<<<N_NODES, blk, 0, stream>>>(h16, as2, ad2, esrc, edst, 1024, 1024, 256, 4);
        agg_big<1><<<N_NODES, blk, 0, stream>>>(h16, esrc, edst, rowptr, perm, b2, xbuf, xh);
    }
    // ---- layer 3: K=1024, H=6, C=121, mean heads + sigmoid ----
    {
        dim3 g(6, 79);
        gemm_mfma<<<g, blk, 0, stream>>>(xh, W3h, h16, N_NODES, 726, 1024, 768);
        attn_kernel<<<N_NODES, blk, 0, stream>>>(h16, as3, ad3, esrc, edst, 768, 726, 121, 6);
        agg_final<<<N_NODES, blk, 0, stream>>>(h16, esrc, edst, rowptr, perm, b3, out);
    }
}